// Round 12
// baseline (2810.144 us; speedup 1.0000x reference)
//
#include <hip/hip_runtime.h>
#include <hip/hip_bf16.h>

#define N_NODES 100000
#define N_EDGES 1600000
#define CH 64
#define NRANGE 8                 // dst-range groups; blockIdx&7 ~ XCD under round-robin
#define CAP (N_EDGES / 4)        // per-bucket capacity (expected E/8=200K, 2x slack)

// ---------------- helpers ----------------

__device__ __forceinline__ unsigned short f2bf(float f) {
    unsigned int u = __float_as_uint(f);
    u += 0x7FFF + ((u >> 16) & 1);          // round-to-nearest-even
    return (unsigned short)(u >> 16);
}
__device__ __forceinline__ float bf2f(unsigned short b) {
    return __uint_as_float(((unsigned int)b) << 16);
}

// ---------------- CSR build: bin -> count -> scan -> fill ----------------

// One pass over edges; wave-ballot compaction appends (dst,src) into 8
// dst-range buckets. Writes are contiguous runs (<=512B per wave per bucket)
// -> bucket lines fully dirtied by one wave, written back ~once. This replaces
// the 8x edge-list re-read AND gives the later scatter a small read stream.
__global__ __launch_bounds__(256) void k_bin(const int* __restrict__ src,
                                             const int* __restrict__ dst,
                                             int* __restrict__ bcur,
                                             int* __restrict__ bsrc,
                                             int* __restrict__ bdst,
                                             int E, int span) {
    int lane    = threadIdx.x & 63;
    int wid     = (blockIdx.x * blockDim.x + threadIdx.x) >> 6;
    int nwaves  = (gridDim.x * blockDim.x) >> 6;
    unsigned long long mask_lt = (lane == 63) ? 0x7FFFFFFFFFFFFFFFull
                                              : ((1ull << lane) - 1ull);
    for (int i0 = wid * 64; i0 < E; i0 += nwaves * 64) {   // i0 wave-uniform
        int i = i0 + lane;
        bool valid = (i < E);
        int d = 0, s = 0, b = -1;
        if (valid) { d = dst[i]; s = src[i]; b = d / span; }
#pragma unroll
        for (int r = 0; r < NRANGE; ++r) {
            unsigned long long m = __ballot(valid && (b == r));
            if (m == 0ull) continue;                        // wave-uniform
            int leader = __ffsll((long long)m) - 1;
            int base = 0;
            if (lane == leader) base = atomicAdd(&bcur[r], __popcll(m));
            base = __shfl(base, leader, 64);
            if (valid && (b == r)) {
                int idx = base + __popcll(m & mask_lt);
                if (idx < CAP) {                            // safety clamp
                    bdst[r * CAP + idx] = d;
                    bsrc[r * CAP + idx] = s;
                }
            }
        }
    }
}

// Range group r counts degrees from its contiguous bucket (~1.6MB, L2-resident
// on one XCD); cnt atomics are XCD-local (dst in owned range only).
__global__ __launch_bounds__(256) void k_count(const int* __restrict__ bcur,
                                               const int* __restrict__ bdst,
                                               int* __restrict__ cnt) {
    int r    = blockIdx.x & (NRANGE - 1);
    int gtid = (blockIdx.x >> 3) * blockDim.x + threadIdx.x;
    int gnth = (gridDim.x >> 3) * blockDim.x;
    int n = bcur[r]; if (n > CAP) n = CAP;
    const int* bp = bdst + r * CAP;
    for (int i = gtid; i < n; i += gnth) atomicAdd(&cnt[bp[i]], 1);
}

__global__ __launch_bounds__(1024) void k_scanA(const int* __restrict__ cnt, int N,
                                                int* __restrict__ rowp, int* __restrict__ bsum) {
    __shared__ int s[1024];
    int t = threadIdx.x;
    int g = blockIdx.x * 1024 + t;
    int v = (g < N) ? cnt[g] : 0;
    s[t] = v;
    __syncthreads();
    for (int off = 1; off < 1024; off <<= 1) {
        int x = (t >= off) ? s[t - off] : 0;
        __syncthreads();
        s[t] += x;
        __syncthreads();
    }
    if (g < N) rowp[g] = s[t] - v;          // exclusive within block
    if (t == 1023) bsum[blockIdx.x] = s[1023];
}

__global__ __launch_bounds__(1024) void k_scanB(int* __restrict__ bsum, int nb) {
    __shared__ int s[1024];
    int t = threadIdx.x;
    int v = (t < nb) ? bsum[t] : 0;
    s[t] = v;
    __syncthreads();
    for (int off = 1; off < 1024; off <<= 1) {
        int x = (t >= off) ? s[t - off] : 0;
        __syncthreads();
        s[t] += x;
        __syncthreads();
    }
    if (t < nb) bsum[t] = s[t] - v;         // exclusive
}

__global__ void k_scanC(int* __restrict__ rowp, const int* __restrict__ cnt,
                        const int* __restrict__ bsum, int* __restrict__ cursor,
                        float* __restrict__ dinv, int N) {
    int g = blockIdx.x * blockDim.x + threadIdx.x;
    if (g < N) {
        int r = rowp[g] + bsum[g >> 10];
        rowp[g]   = r;
        cursor[g] = r;
        int d = cnt[g];
        dinv[g] = 1.0f / (float)(d > 1 ? d : 1);
    }
}

// Range group r scatters its bucket into its col window (~0.8MB). Read stream
// (1.6MB bucket) + write window both fit ONE XCD's 4MB L2 -> dirty col lines
// survive until a single final writeback (round-11 showed the 12.8MB edge
// stream evicting dirty lines was the remaining write-amplification source).
__global__ __launch_bounds__(256) void k_fill2(const int* __restrict__ bcur,
                                               const int* __restrict__ bsrc,
                                               const int* __restrict__ bdst,
                                               int* __restrict__ cursor,
                                               int* __restrict__ col) {
    int r    = blockIdx.x & (NRANGE - 1);
    int gtid = (blockIdx.x >> 3) * blockDim.x + threadIdx.x;
    int gnth = (gridDim.x >> 3) * blockDim.x;
    int n = bcur[r]; if (n > CAP) n = CAP;
    const int* bd = bdst + r * CAP;
    const int* bs = bsrc + r * CAP;
    for (int i = gtid; i < n; i += gnth) {
        int d = bd[i];
        int s = bs[i];
        col[atomicAdd(&cursor[d], 1)] = s;
    }
}

// ---------------- dense transform ----------------
// T[n][o] = sum_c h[n][c]*Wl[o][c]   (bf16, consumed only via mean -> error ~2.5e-4)
// S[n][o] = bl[o] + sum_c h[n][c]*Wr[o][c]
// lane = o. Weight rows live in registers (128 VGPR); h[c] broadcast via readlane.
__global__ __launch_bounds__(256) void k_transform(const float* __restrict__ h,
                                                   const float* __restrict__ Wl,
                                                   const float* __restrict__ bl,
                                                   const float* __restrict__ Wr,
                                                   unsigned short* __restrict__ T,
                                                   float* __restrict__ S, int N) {
    int lane = threadIdx.x & 63;
    float wl[CH], wr[CH];
    const float4* Wl4 = (const float4*)(Wl + lane * CH);
    const float4* Wr4 = (const float4*)(Wr + lane * CH);
#pragma unroll
    for (int q = 0; q < CH / 4; ++q) {
        float4 a = Wl4[q];
        wl[4 * q] = a.x; wl[4 * q + 1] = a.y; wl[4 * q + 2] = a.z; wl[4 * q + 3] = a.w;
        float4 b = Wr4[q];
        wr[4 * q] = b.x; wr[4 * q + 1] = b.y; wr[4 * q + 2] = b.z; wr[4 * q + 3] = b.w;
    }
    float bias = bl[lane];

    int wid    = (blockIdx.x * blockDim.x + threadIdx.x) >> 6;
    int nwaves = (gridDim.x * blockDim.x) >> 6;
    for (int n = wid; n < N; n += nwaves) {
        float hv = h[n * CH + lane];
        float ol = 0.f, orr = 0.f;
#pragma unroll
        for (int c = 0; c < CH; ++c) {
            float hc = __uint_as_float(__builtin_amdgcn_readlane(__float_as_uint(hv), c));
            ol  += hc * wl[c];
            orr += hc * wr[c];
        }
        T[n * CH + lane] = f2bf(ol);
        S[n * CH + lane] = orr + bias;
    }
}

// ---------------- gather ----------------
// out[n][c] = relu?( S[n][c] + dinv[n] * sum_e T[col[e]][c] )
// one node per 32-lane half (2 nodes/wave); uint load = 2 bf16 channels/lane;
// unroll 8 -> 8 edge-row loads in flight per half-wave (latency hiding).
__global__ __launch_bounds__(256) void k_gather(const unsigned short* __restrict__ T,
                                                const float* __restrict__ S,
                                                const int* __restrict__ rowp,
                                                const int* __restrict__ cnt,
                                                const float* __restrict__ dinv,
                                                const int* __restrict__ col,
                                                float* __restrict__ out,
                                                int relu, int N) {
    int li = threadIdx.x & 31;
    int n  = blockIdx.x * 8 + (threadIdx.x >> 5);
    if (n >= N) return;

    int start = rowp[n];
    int deg   = cnt[n];
    const int* cp = col + start;

    float a0 = 0.f, a1 = 0.f, b0 = 0.f, b1 = 0.f;
    float c0 = 0.f, c1 = 0.f, d0 = 0.f, d1 = 0.f;
    int e = 0;
    for (; e + 8 <= deg; e += 8) {
        int s0 = cp[e + 0];
        int s1 = cp[e + 1];
        int s2 = cp[e + 2];
        int s3 = cp[e + 3];
        int s4 = cp[e + 4];
        int s5 = cp[e + 5];
        int s6 = cp[e + 6];
        int s7 = cp[e + 7];
        unsigned u0 = *(const unsigned*)(T + (size_t)s0 * CH + 2 * li);
        unsigned u1 = *(const unsigned*)(T + (size_t)s1 * CH + 2 * li);
        unsigned u2 = *(const unsigned*)(T + (size_t)s2 * CH + 2 * li);
        unsigned u3 = *(const unsigned*)(T + (size_t)s3 * CH + 2 * li);
        unsigned u4 = *(const unsigned*)(T + (size_t)s4 * CH + 2 * li);
        unsigned u5 = *(const unsigned*)(T + (size_t)s5 * CH + 2 * li);
        unsigned u6 = *(const unsigned*)(T + (size_t)s6 * CH + 2 * li);
        unsigned u7 = *(const unsigned*)(T + (size_t)s7 * CH + 2 * li);
        a0 += bf2f((unsigned short)u0); a1 += bf2f((unsigned short)(u0 >> 16));
        b0 += bf2f((unsigned short)u1); b1 += bf2f((unsigned short)(u1 >> 16));
        c0 += bf2f((unsigned short)u2); c1 += bf2f((unsigned short)(u2 >> 16));
        d0 += bf2f((unsigned short)u3); d1 += bf2f((unsigned short)(u3 >> 16));
        a0 += bf2f((unsigned short)u4); a1 += bf2f((unsigned short)(u4 >> 16));
        b0 += bf2f((unsigned short)u5); b1 += bf2f((unsigned short)(u5 >> 16));
        c0 += bf2f((unsigned short)u6); c1 += bf2f((unsigned short)(u6 >> 16));
        d0 += bf2f((unsigned short)u7); d1 += bf2f((unsigned short)(u7 >> 16));
    }
    for (; e < deg; ++e) {
        int s = cp[e];
        unsigned u = *(const unsigned*)(T + (size_t)s * CH + 2 * li);
        a0 += bf2f((unsigned short)u); a1 += bf2f((unsigned short)(u >> 16));
    }
    float r0 = (a0 + b0) + (c0 + d0);
    float r1 = (a1 + b1) + (c1 + d1);

    float dv = dinv[n];
    float2 sv = *(const float2*)(S + (size_t)n * CH + 2 * li);
    float o0 = sv.x + r0 * dv;
    float o1 = sv.y + r1 * dv;
    if (relu) { o0 = fmaxf(o0, 0.f); o1 = fmaxf(o1, 0.f); }
    *(float2*)(out + (size_t)n * CH + 2 * li) = make_float2(o0, o1);
}

// ---------------- launch ----------------

extern "C" void kernel_launch(void* const* d_in, const int* in_sizes, int n_in,
                              void* d_out, int out_size, void* d_ws, size_t ws_size,
                              hipStream_t stream) {
    const float* x   = (const float*)d_in[0];
    const int*   ei  = (const int*)d_in[1];
    const int E = in_sizes[1] / 2;
    const int N = in_sizes[0] / CH;
    const int* src = ei;
    const int* dst = ei + E;

    const float* Wl[3] = { (const float*)d_in[2], (const float*)d_in[5], (const float*)d_in[8] };
    const float* bl[3] = { (const float*)d_in[3], (const float*)d_in[6], (const float*)d_in[9] };
    const float* Wr[3] = { (const float*)d_in[4], (const float*)d_in[7], (const float*)d_in[10] };

    char* ws = (char*)d_ws;
    size_t off = 0;
    auto take = [&](size_t bytes) { char* p = ws + off; off += (bytes + 255) & ~(size_t)255; return p; };
    int*            cnt    = (int*)           take((size_t)N * 4);
    int*            rowp   = (int*)           take((size_t)(N + 1) * 4);
    int*            cursor = (int*)           take((size_t)N * 4);
    float*          dinv   = (float*)         take((size_t)N * 4);
    int*            bsum   = (int*)           take(4096);
    int*            bcur   = (int*)           take(256);
    int*            col    = (int*)           take((size_t)E * 4);
    int*            bsrc   = (int*)           take((size_t)NRANGE * CAP * 4);
    int*            bdst   = (int*)           take((size_t)NRANGE * CAP * 4);
    unsigned short* T      = (unsigned short*)take((size_t)N * CH * 2);
    float*          S      = (float*)         take((size_t)N * CH * 4);
    float*          buf0   = (float*)         take((size_t)N * CH * 4);
    float*          outp   = (float*)d_out;

    hipMemsetAsync(cnt, 0, (size_t)N * 4, stream);
    hipMemsetAsync(bcur, 0, 256, stream);

    int tb = 256;
    int span = (N + NRANGE - 1) / NRANGE;
    k_bin<<<1024, tb, 0, stream>>>(src, dst, bcur, bsrc, bdst, E, span);
    k_count<<<1024, tb, 0, stream>>>(bcur, bdst, cnt);

    int nb = (N + 1023) / 1024;
    k_scanA<<<nb, 1024, 0, stream>>>(cnt, N, rowp, bsum);
    k_scanB<<<1, 1024, 0, stream>>>(bsum, nb);
    k_scanC<<<(N + tb - 1) / tb, tb, 0, stream>>>(rowp, cnt, bsum, cursor, dinv, N);
    k_fill2<<<1024, tb, 0, stream>>>(bcur, bsrc, bdst, cursor, col);

    int gblocks = (N + 7) / 8;   // 8 nodes per 256-thread block (1 per 32-lane half)
    // layer 0
    k_transform<<<1024, 256, 0, stream>>>(x, Wl[0], bl[0], Wr[0], T, S, N);
    k_gather<<<gblocks, 256, 0, stream>>>(T, S, rowp, cnt, dinv, col, buf0, 1, N);
    // layer 1
    k_transform<<<1024, 256, 0, stream>>>(buf0, Wl[1], bl[1], Wr[1], T, S, N);
    k_gather<<<gblocks, 256, 0, stream>>>(T, S, rowp, cnt, dinv, col, buf0, 1, N);
    // layer 2
    k_transform<<<1024, 256, 0, stream>>>(buf0, Wl[2], bl[2], Wr[2], T, S, N);
    k_gather<<<gblocks, 256, 0, stream>>>(T, S, rowp, cnt, dinv, col, outp, 0, N);
}

// Round 14
// 554.456 us; speedup vs baseline: 5.0683x; 5.0683x over previous
//
#include <hip/hip_runtime.h>
#include <hip/hip_bf16.h>

#define N_NODES 100000
#define N_EDGES 1600000
#define CH 64
#define NRANGE 8                 // dst-range groups; blockIdx&7 ~ XCD under round-robin
#define CAP (N_EDGES / 4)        // per-bucket capacity (expected E/8=200K, 2x slack)
#define LCAP 384                 // LDS bucket entries per range per chunk (8 sigma slack)
#define CHUNK 2048               // edges per block-chunk (8 per thread)

// ---------------- helpers ----------------

__device__ __forceinline__ unsigned short f2bf(float f) {
    unsigned int u = __float_as_uint(f);
    u += 0x7FFF + ((u >> 16) & 1);          // round-to-nearest-even
    return (unsigned short)(u >> 16);
}
__device__ __forceinline__ float bf2f(unsigned short b) {
    return __uint_as_float(((unsigned int)b) << 16);
}

// ---------------- CSR build: bin -> count -> scan -> fill ----------------

// Chunked LDS-staged partitioner. Block classifies CHUNK edges into 8 LDS
// buckets (LDS atomics, block-local), then flushes each bucket with ONE global
// atomicAdd reservation + coalesced run-write. Round 12's failure mode
// (200K serialized global atomics on 8 hot words, 2272us) becomes ~6K
// block-aggregated reservations.
__global__ __launch_bounds__(256) void k_bin(const int* __restrict__ src,
                                             const int* __restrict__ dst,
                                             int* __restrict__ bcur,
                                             int* __restrict__ bsrc,
                                             int* __restrict__ bdst,
                                             int E, int span) {
    __shared__ int lcnt[NRANGE];
    __shared__ int lbase[NRANGE];
    __shared__ int lbd[NRANGE][LCAP];
    __shared__ int lbs[NRANGE][LCAP];
    int tid = threadIdx.x;

    for (int base = blockIdx.x * CHUNK; base < E; base += gridDim.x * CHUNK) {
        if (tid < NRANGE) lcnt[tid] = 0;
        __syncthreads();

#pragma unroll
        for (int k = 0; k < CHUNK / 256; ++k) {
            int i = base + k * 256 + tid;
            if (i < E) {
                int d = dst[i];
                int s = src[i];
                int r = d / span;
                int pos = atomicAdd(&lcnt[r], 1);
                if (pos < LCAP) {
                    lbd[r][pos] = d;
                    lbs[r][pos] = s;
                } else {                         // statistically ~never
                    int gi = atomicAdd(&bcur[r], 1);
                    if (gi < CAP) { bdst[r * CAP + gi] = d; bsrc[r * CAP + gi] = s; }
                }
            }
        }
        __syncthreads();

        if (tid < NRANGE) {
            int c = lcnt[tid]; if (c > LCAP) c = LCAP;
            lcnt[tid]  = c;
            lbase[tid] = atomicAdd(&bcur[tid], c);
        }
        __syncthreads();

#pragma unroll
        for (int r = 0; r < NRANGE; ++r) {
            int c = lcnt[r];
            int b = lbase[r];
            for (int i = tid; i < c; i += 256) {
                int gi = b + i;
                if (gi < CAP) {
                    bdst[r * CAP + gi] = lbd[r][i];
                    bsrc[r * CAP + gi] = lbs[r][i];
                }
            }
        }
        __syncthreads();
    }
}

// Range group r counts degrees from its contiguous bucket (~0.8MB, L2-resident
// on one XCD); cnt atomics are XCD-local (dst in owned range only).
__global__ __launch_bounds__(256) void k_count(const int* __restrict__ bcur,
                                               const int* __restrict__ bdst,
                                               int* __restrict__ cnt) {
    int r    = blockIdx.x & (NRANGE - 1);
    int gtid = (blockIdx.x >> 3) * blockDim.x + threadIdx.x;
    int gnth = (gridDim.x >> 3) * blockDim.x;
    int n = bcur[r]; if (n > CAP) n = CAP;
    const int* bp = bdst + r * CAP;
    for (int i = gtid; i < n; i += gnth) atomicAdd(&cnt[bp[i]], 1);
}

__global__ __launch_bounds__(1024) void k_scanA(const int* __restrict__ cnt, int N,
                                                int* __restrict__ rowp, int* __restrict__ bsum) {
    __shared__ int s[1024];
    int t = threadIdx.x;
    int g = blockIdx.x * 1024 + t;
    int v = (g < N) ? cnt[g] : 0;
    s[t] = v;
    __syncthreads();
    for (int off = 1; off < 1024; off <<= 1) {
        int x = (t >= off) ? s[t - off] : 0;
        __syncthreads();
        s[t] += x;
        __syncthreads();
    }
    if (g < N) rowp[g] = s[t] - v;          // exclusive within block
    if (t == 1023) bsum[blockIdx.x] = s[1023];
}

__global__ __launch_bounds__(1024) void k_scanB(int* __restrict__ bsum, int nb) {
    __shared__ int s[1024];
    int t = threadIdx.x;
    int v = (t < nb) ? bsum[t] : 0;
    s[t] = v;
    __syncthreads();
    for (int off = 1; off < 1024; off <<= 1) {
        int x = (t >= off) ? s[t - off] : 0;
        __syncthreads();
        s[t] += x;
        __syncthreads();
    }
    if (t < nb) bsum[t] = s[t] - v;         // exclusive
}

__global__ void k_scanC(int* __restrict__ rowp, const int* __restrict__ cnt,
                        const int* __restrict__ bsum, int* __restrict__ cursor,
                        float* __restrict__ dinv, int N) {
    int g = blockIdx.x * blockDim.x + threadIdx.x;
    if (g < N) {
        int r = rowp[g] + bsum[g >> 10];
        rowp[g]   = r;
        cursor[g] = r;
        int d = cnt[g];
        dinv[g] = 1.0f / (float)(d > 1 ? d : 1);
    }
}

// Range group r scatters its bucket into its col window (~0.8MB). Read stream
// (1.6MB bucket) + write window both fit ONE XCD's 4MB L2 -> dirty col lines
// survive until a single final writeback (round-11 showed the 12.8MB edge
// stream evicting dirty lines was the remaining write-amplification source).
__global__ __launch_bounds__(256) void k_fill2(const int* __restrict__ bcur,
                                               const int* __restrict__ bsrc,
                                               const int* __restrict__ bdst,
                                               int* __restrict__ cursor,
                                               int* __restrict__ col) {
    int r    = blockIdx.x & (NRANGE - 1);
    int gtid = (blockIdx.x >> 3) * blockDim.x + threadIdx.x;
    int gnth = (gridDim.x >> 3) * blockDim.x;
    int n = bcur[r]; if (n > CAP) n = CAP;
    const int* bd = bdst + r * CAP;
    const int* bs = bsrc + r * CAP;
    for (int i = gtid; i < n; i += gnth) {
        int d = bd[i];
        int s = bs[i];
        col[atomicAdd(&cursor[d], 1)] = s;
    }
}

// ---------------- dense transform ----------------
// T[n][o] = sum_c h[n][c]*Wl[o][c]   (bf16, consumed only via mean -> error ~2.5e-4)
// S[n][o] = bl[o] + sum_c h[n][c]*Wr[o][c]
// lane = o. Weight rows live in registers (128 VGPR); h[c] broadcast via readlane.
__global__ __launch_bounds__(256) void k_transform(const float* __restrict__ h,
                                                   const float* __restrict__ Wl,
                                                   const float* __restrict__ bl,
                                                   const float* __restrict__ Wr,
                                                   unsigned short* __restrict__ T,
                                                   float* __restrict__ S, int N) {
    int lane = threadIdx.x & 63;
    float wl[CH], wr[CH];
    const float4* Wl4 = (const float4*)(Wl + lane * CH);
    const float4* Wr4 = (const float4*)(Wr + lane * CH);
#pragma unroll
    for (int q = 0; q < CH / 4; ++q) {
        float4 a = Wl4[q];
        wl[4 * q] = a.x; wl[4 * q + 1] = a.y; wl[4 * q + 2] = a.z; wl[4 * q + 3] = a.w;
        float4 b = Wr4[q];
        wr[4 * q] = b.x; wr[4 * q + 1] = b.y; wr[4 * q + 2] = b.z; wr[4 * q + 3] = b.w;
    }
    float bias = bl[lane];

    int wid    = (blockIdx.x * blockDim.x + threadIdx.x) >> 6;
    int nwaves = (gridDim.x * blockDim.x) >> 6;
    for (int n = wid; n < N; n += nwaves) {
        float hv = h[n * CH + lane];
        float ol = 0.f, orr = 0.f;
#pragma unroll
        for (int c = 0; c < CH; ++c) {
            float hc = __uint_as_float(__builtin_amdgcn_readlane(__float_as_uint(hv), c));
            ol  += hc * wl[c];
            orr += hc * wr[c];
        }
        T[n * CH + lane] = f2bf(ol);
        S[n * CH + lane] = orr + bias;
    }
}

// ---------------- gather ----------------
// out[n][c] = relu?( S[n][c] + dinv[n] * sum_e T[col[e]][c] )
// one node per 32-lane half (2 nodes/wave); uint load = 2 bf16 channels/lane;
// unroll 8 -> 8 edge-row loads in flight per half-wave (latency hiding).
__global__ __launch_bounds__(256) void k_gather(const unsigned short* __restrict__ T,
                                                const float* __restrict__ S,
                                                const int* __restrict__ rowp,
                                                const int* __restrict__ cnt,
                                                const float* __restrict__ dinv,
                                                const int* __restrict__ col,
                                                float* __restrict__ out,
                                                int relu, int N) {
    int li = threadIdx.x & 31;
    int n  = blockIdx.x * 8 + (threadIdx.x >> 5);
    if (n >= N) return;

    int start = rowp[n];
    int deg   = cnt[n];
    const int* cp = col + start;

    float a0 = 0.f, a1 = 0.f, b0 = 0.f, b1 = 0.f;
    float c0 = 0.f, c1 = 0.f, d0 = 0.f, d1 = 0.f;
    int e = 0;
    for (; e + 8 <= deg; e += 8) {
        int s0 = cp[e + 0];
        int s1 = cp[e + 1];
        int s2 = cp[e + 2];
        int s3 = cp[e + 3];
        int s4 = cp[e + 4];
        int s5 = cp[e + 5];
        int s6 = cp[e + 6];
        int s7 = cp[e + 7];
        unsigned u0 = *(const unsigned*)(T + (size_t)s0 * CH + 2 * li);
        unsigned u1 = *(const unsigned*)(T + (size_t)s1 * CH + 2 * li);
        unsigned u2 = *(const unsigned*)(T + (size_t)s2 * CH + 2 * li);
        unsigned u3 = *(const unsigned*)(T + (size_t)s3 * CH + 2 * li);
        unsigned u4 = *(const unsigned*)(T + (size_t)s4 * CH + 2 * li);
        unsigned u5 = *(const unsigned*)(T + (size_t)s5 * CH + 2 * li);
        unsigned u6 = *(const unsigned*)(T + (size_t)s6 * CH + 2 * li);
        unsigned u7 = *(const unsigned*)(T + (size_t)s7 * CH + 2 * li);
        a0 += bf2f((unsigned short)u0); a1 += bf2f((unsigned short)(u0 >> 16));
        b0 += bf2f((unsigned short)u1); b1 += bf2f((unsigned short)(u1 >> 16));
        c0 += bf2f((unsigned short)u2); c1 += bf2f((unsigned short)(u2 >> 16));
        d0 += bf2f((unsigned short)u3); d1 += bf2f((unsigned short)(u3 >> 16));
        a0 += bf2f((unsigned short)u4); a1 += bf2f((unsigned short)(u4 >> 16));
        b0 += bf2f((unsigned short)u5); b1 += bf2f((unsigned short)(u5 >> 16));
        c0 += bf2f((unsigned short)u6); c1 += bf2f((unsigned short)(u6 >> 16));
        d0 += bf2f((unsigned short)u7); d1 += bf2f((unsigned short)(u7 >> 16));
    }
    for (; e < deg; ++e) {
        int s = cp[e];
        unsigned u = *(const unsigned*)(T + (size_t)s * CH + 2 * li);
        a0 += bf2f((unsigned short)u); a1 += bf2f((unsigned short)(u >> 16));
    }
    float r0 = (a0 + b0) + (c0 + d0);
    float r1 = (a1 + b1) + (c1 + d1);

    float dv = dinv[n];
    float2 sv = *(const float2*)(S + (size_t)n * CH + 2 * li);
    float o0 = sv.x + r0 * dv;
    float o1 = sv.y + r1 * dv;
    if (relu) { o0 = fmaxf(o0, 0.f); o1 = fmaxf(o1, 0.f); }
    *(float2*)(out + (size_t)n * CH + 2 * li) = make_float2(o0, o1);
}

// ---------------- launch ----------------

extern "C" void kernel_launch(void* const* d_in, const int* in_sizes, int n_in,
                              void* d_out, int out_size, void* d_ws, size_t ws_size,
                              hipStream_t stream) {
    const float* x   = (const float*)d_in[0];
    const int*   ei  = (const int*)d_in[1];
    const int E = in_sizes[1] / 2;
    const int N = in_sizes[0] / CH;
    const int* src = ei;
    const int* dst = ei + E;

    const float* Wl[3] = { (const float*)d_in[2], (const float*)d_in[5], (const float*)d_in[8] };
    const float* bl[3] = { (const float*)d_in[3], (const float*)d_in[6], (const float*)d_in[9] };
    const float* Wr[3] = { (const float*)d_in[4], (const float*)d_in[7], (const float*)d_in[10] };

    char* ws = (char*)d_ws;
    size_t off = 0;
    auto take = [&](size_t bytes) { char* p = ws + off; off += (bytes + 255) & ~(size_t)255; return p; };
    int*            cnt    = (int*)           take((size_t)N * 4);
    int*            rowp   = (int*)           take((size_t)(N + 1) * 4);
    int*            cursor = (int*)           take((size_t)N * 4);
    float*          dinv   = (float*)         take((size_t)N * 4);
    int*            bsum   = (int*)           take(4096);
    int*            bcur   = (int*)           take(256);
    int*            col    = (int*)           take((size_t)E * 4);
    int*            bsrc   = (int*)           take((size_t)NRANGE * CAP * 4);
    int*            bdst   = (int*)           take((size_t)NRANGE * CAP * 4);
    unsigned short* T      = (unsigned short*)take((size_t)N * CH * 2);
    float*          S      = (float*)         take((size_t)N * CH * 4);
    float*          buf0   = (float*)         take((size_t)N * CH * 4);
    float*          outp   = (float*)d_out;

    hipMemsetAsync(cnt, 0, (size_t)N * 4, stream);
    hipMemsetAsync(bcur, 0, 256, stream);

    int tb = 256;
    int span = (N + NRANGE - 1) / NRANGE;
    k_bin<<<(N_EDGES + CHUNK - 1) / CHUNK, tb, 0, stream>>>(src, dst, bcur, bsrc, bdst, E, span);
    k_count<<<1024, tb, 0, stream>>>(bcur, bdst, cnt);

    int nb = (N + 1023) / 1024;
    k_scanA<<<nb, 1024, 0, stream>>>(cnt, N, rowp, bsum);
    k_scanB<<<1, 1024, 0, stream>>>(bsum, nb);
    k_scanC<<<(N + tb - 1) / tb, tb, 0, stream>>>(rowp, cnt, bsum, cursor, dinv, N);
    k_fill2<<<1024, tb, 0, stream>>>(bcur, bsrc, bdst, cursor, col);

    int gblocks = (N + 7) / 8;   // 8 nodes per 256-thread block (1 per 32-lane half)
    // layer 0
    k_transform<<<1024, 256, 0, stream>>>(x, Wl[0], bl[0], Wr[0], T, S, N);
    k_gather<<<gblocks, 256, 0, stream>>>(T, S, rowp, cnt, dinv, col, buf0, 1, N);
    // layer 1
    k_transform<<<1024, 256, 0, stream>>>(buf0, Wl[1], bl[1], Wr[1], T, S, N);
    k_gather<<<gblocks, 256, 0, stream>>>(T, S, rowp, cnt, dinv, col, buf0, 1, N);
    // layer 2
    k_transform<<<1024, 256, 0, stream>>>(buf0, Wl[2], bl[2], Wr[2], T, S, N);
    k_gather<<<gblocks, 256, 0, stream>>>(T, S, rowp, cnt, dinv, col, outp, 0, N);
}